// Round 11
// baseline (595.043 us; speedup 1.0000x reference)
//
#include <hip/hip_runtime.h>
#include <math.h>

#define HH 480
#define WW 640
#define NPIX (HH*WW)
#define NACC 29            // 21 (A upper tri) + 6 (b) + 1 r_icp^2 + 1 r_rgb^2
#define TPB_B 512
#define NB_B 600           // 600*512 = 307200 = NPIX exact, 1 px/thread
#define PB 600             // partials row stride
#define NSPL 16            // stage-1 split per q
#define CHS 38             // ceil(600/16); last split reads 30

// d_ws float-index layout. First 256 BYTES zeroed by captured hipMemsetAsync.
//   [0..11]   pose: R row-major(9), t(3)  (written by pack_init/finisher)
//   [12]      conv flag   [13] cost   [16..21] x(6)
//   int[32..51] per-iteration finish counters (bytes 128..208)
//   [WS_P..)  partials transposed [q][block], 29*600 floats (sc1-only)
//   PACKED only:
//   [WS_G4..) float4/px (grayT, gx, gy, 0)
//   [WS_NR..) float4/px (nr0, nr1, nr2, depth_ref)
//   [WS_PZ..) float4/px (qz, nq0, nq1, nq2)
#define WS_P 512
#define WS_G4 18432                       // 16B-aligned
#define WS_NR (WS_G4 + NPIX*4)
#define WS_PZ (WS_NR + NPIX*4)
#define WS_BIG_END (WS_PZ + NPIX*4)       // ~14.82 MB

__device__ __forceinline__ float ld_f_sc1(const float* p) {
    return __hip_atomic_load(p, __ATOMIC_RELAXED, __HIP_MEMORY_SCOPE_AGENT);
}
__device__ __forceinline__ void st_f_sc1(float* p, float v) {
    __hip_atomic_store(p, v, __ATOMIC_RELAXED, __HIP_MEMORY_SCOPE_AGENT);
}

__device__ __forceinline__ float gradu(const float* g, int v, int u) {
    const float* row = g + v * WW;
    if (u == 0)      return row[1] - row[0];
    if (u == WW - 1) return row[WW - 1] - row[WW - 2];
    return 0.5f * (row[u + 1] - row[u - 1]);
}
__device__ __forceinline__ float gradv(const float* g, int v, int u) {
    if (v == 0)      return g[WW + u] - g[u];
    if (v == HH - 1) return g[(HH - 1) * WW + u] - g[(HH - 2) * WW + u];
    return 0.5f * (g[(v + 1) * WW + u] - g[(v - 1) * WW + u]);
}

__device__ void exp_se3_f32(const float* xi, float* T) {
    float v0 = xi[0], v1 = xi[1], v2 = xi[2];
    float w0 = xi[3], w1 = xi[4], w2 = xi[5];
    float th2 = w0 * w0 + w1 * w1 + w2 * w2;
    float th = sqrtf(th2);
    bool small = th < 1e-8f;
    float ths = small ? 1.0f : th;
    float A = small ? (1.0f - th2 / 6.0f) : (sinf(ths) / ths);
    float B = small ? (0.5f - th2 / 24.0f) : ((1.0f - cosf(ths)) / (ths * ths));
    float C = small ? (1.0f / 6.0f - th2 / 120.0f) : ((ths - sinf(ths)) / (ths * ths * ths));
    float Wx[9] = { 0.f, -w2,  w1,
                    w2,  0.f, -w0,
                   -w1,  w0,  0.f };
    float W2[9];
    #pragma unroll
    for (int i = 0; i < 3; i++)
        #pragma unroll
        for (int j = 0; j < 3; j++) {
            float s = 0.f;
            #pragma unroll
            for (int k = 0; k < 3; k++) s += Wx[i * 3 + k] * Wx[k * 3 + j];
            W2[i * 3 + j] = s;
        }
    float R[9], V[9];
    #pragma unroll
    for (int i = 0; i < 9; i++) {
        float id = (i == 0 || i == 4 || i == 8) ? 1.0f : 0.0f;
        R[i] = id + A * Wx[i] + B * W2[i];
        V[i] = id + B * Wx[i] + C * W2[i];
    }
    float t0 = V[0] * v0 + V[1] * v1 + V[2] * v2;
    float t1 = V[3] * v0 + V[4] * v1 + V[5] * v2;
    float t2 = V[6] * v0 + V[7] * v1 + V[8] * v2;
    T[0] = R[0]; T[1] = R[1]; T[2]  = R[2]; T[3]  = t0;
    T[4] = R[3]; T[5] = R[4]; T[6]  = R[5]; T[7]  = t1;
    T[8] = R[6]; T[9] = R[7]; T[10] = R[8]; T[11] = t2;
    T[12] = 0.f; T[13] = 0.f; T[14] = 0.f; T[15] = 1.f;
}

__device__ __forceinline__ void accum_point(float* acc, const float* J, float r, float w, int costslot) {
    int k = 0;
    #pragma unroll
    for (int i = 0; i < 6; i++) {
        #pragma unroll
        for (int j = i; j < 6; j++) { acc[k] += w * (J[i] * J[j]); k++; }
        acc[21 + i] += w * (J[i] * r);
    }
    acc[costslot] += r * r;
}

// ---- Kernel A: one-time state init + packed-texture build ----
template <int PACKED>
__global__ __launch_bounds__(TPB_B) void pack_init(
    const float* __restrict__ depth_ref,
    const float* __restrict__ normals_ref,
    const float* __restrict__ gray_target,
    const float* __restrict__ points_target,
    const float* __restrict__ normals_target,
    float* __restrict__ ws)
{
    if (blockIdx.x == 0 && threadIdx.x == 0) {
        ws[0] = 1.f; ws[1] = 0.f; ws[2] = 0.f;
        ws[3] = 0.f; ws[4] = 1.f; ws[5] = 0.f;
        ws[6] = 0.f; ws[7] = 0.f; ws[8] = 1.f;
        ws[9] = 0.f; ws[10] = 0.f; ws[11] = 0.f;
        ws[12] = 0.f; ws[13] = 0.f;
        #pragma unroll
        for (int i = 0; i < 6; i++) ws[16 + i] = 0.f;
    }
    if (PACKED) {
        int p = blockIdx.x * TPB_B + threadIdx.x;
        int v = p / WW, u = p - v * WW;
        float4* g4  = (float4*)(ws + WS_G4);
        float4* nr4 = (float4*)(ws + WS_NR);
        float4* pz4 = (float4*)(ws + WS_PZ);
        float4 c;
        c.x = gray_target[p];
        c.y = gradu(gray_target, v, u);
        c.z = gradv(gray_target, v, u);
        c.w = 0.f;
        g4[p] = c;
        float4 n;
        n.x = normals_ref[3 * p];
        n.y = normals_ref[3 * p + 1];
        n.z = normals_ref[3 * p + 2];
        n.w = depth_ref[p];
        nr4[p] = n;
        float4 z;
        z.x = points_target[3 * p + 2];
        z.y = normals_target[3 * p];
        z.z = normals_target[3 * p + 1];
        z.w = normals_target[3 * p + 2];
        pz4[p] = z;
    }
}

// ---- Kernel B: map + block-reduce; LAST block also does final reduce+solve.
// No spins anywhere: non-last blocks exit after one fetch_add -> hang-proof
// under any occupancy. Partials cross blocks via relaxed agent-scope (L2-
// bypassing) ops; state crosses DISPATCHES via plain stores (kernel-end release).
template <int PACKED>
__global__ __launch_bounds__(TPB_B, 4) void map_fused(
    const float* __restrict__ depth_ref,
    const float* __restrict__ normals_ref,
    const float* __restrict__ gray_ref,
    const float* __restrict__ gray_target,
    const float* __restrict__ points_target,
    const float* __restrict__ normals_target,
    const float* __restrict__ K,
    float* __restrict__ ws,
    float* __restrict__ out,
    int it)
{
    const int tid = threadIdx.x;
    const int bid = blockIdx.x;
    const float fx = K[0], cx = K[2], fy = K[4], cy = K[5];
    const float4* g4  = (const float4*)(ws + WS_G4);
    const float4* nr4 = (const float4*)(ws + WS_NR);
    const float4* pz4 = (const float4*)(ws + WS_PZ);
    float* pbuf = ws + WS_P;
    int* cnt = (int*)ws + 32 + it;

    __shared__ float spose[12];
    __shared__ float lds[8][NACC];
    __shared__ int slast;
    if (tid < 12) spose[tid] = ws[tid];
    __syncthreads();
    const float R00 = spose[0], R01 = spose[1], R02 = spose[2];
    const float R10 = spose[3], R11 = spose[4], R12 = spose[5];
    const float R20 = spose[6], R21 = spose[7], R22 = spose[8];
    const float t0 = spose[9], t1 = spose[10], t2 = spose[11];

    float acc[NACC];
    #pragma unroll
    for (int i = 0; i < NACC; i++) acc[i] = 0.f;

    {
        int p = bid * TPB_B + tid;        // exactly 1 px/thread
        int vv = p / WW;
        int uu = p - vv * WW;

        float nr0, nr1, nr2, Z;
        if (PACKED) {
            float4 n = nr4[p];
            nr0 = n.x; nr1 = n.y; nr2 = n.z; Z = n.w;
        } else {
            Z = depth_ref[p];
            nr0 = normals_ref[3 * p]; nr1 = normals_ref[3 * p + 1]; nr2 = normals_ref[3 * p + 2];
        }
        float Px = ((float)uu - cx) / fx * Z;
        float Py = ((float)vv - cy) / fy * Z;
        float Pz = Z;
        float Ptx = R00 * Px + R01 * Py + R02 * Pz + t0;
        float Pty = R10 * Px + R11 * Py + R12 * Pz + t1;
        float Ptz = R20 * Px + R21 * Py + R22 * Pz + t2;
        bool okz = Ptz > 1e-6f;
        float Zs = okz ? Ptz : 1.0f;
        float u = fx * Ptx / Zs + cx;
        float v = fy * Pty / Zs + cy;
        bool inb = okz && (u >= 0.f) && (u <= (float)(WW - 1)) && (v >= 0.f) && (v <= (float)(HH - 1));
        if (inb) {
            // ---- ICP term ----
            int ui = (int)rintf(u); ui = ui < 0 ? 0 : (ui > WW - 1 ? WW - 1 : ui);
            int vi = (int)rintf(v); vi = vi < 0 ? 0 : (vi > HH - 1 ? HH - 1 : vi);
            int ti = vi * WW + ui;
            float qx, qy, qz, nqx, nqy, nqz;
            if (PACKED) {
                float4 z = pz4[ti];
                qz = z.x; nqx = z.y; nqy = z.z; nqz = z.w;
                qx = (((float)ui) - cx) / fx * qz;   // bitwise == setup's chain
                qy = (((float)vi) - cy) / fy * qz;
            } else {
                qx = points_target[3 * ti]; qy = points_target[3 * ti + 1]; qz = points_target[3 * ti + 2];
                nqx = normals_target[3 * ti]; nqy = normals_target[3 * ti + 1]; nqz = normals_target[3 * ti + 2];
            }
            float dx = Ptx - qx, dy = Pty - qy, dz = Ptz - qz;
            float nrx = R00 * nr0 + R01 * nr1 + R02 * nr2;
            float nry = R10 * nr0 + R11 * nr1 + R12 * nr2;
            float nrz = R20 * nr0 + R21 * nr1 + R22 * nr2;
            const float DIST2 = (float)((200.0 / 15.0) * (200.0 / 15.0));
            if ((dx * dx + dy * dy + dz * dz) < DIST2 &&
                (nrx * nqx + nry * nqy + nrz * nqz) > 0.94f) {
                float r = nqx * dx + nqy * dy + nqz * dz;
                float J[6] = { nqx, nqy, nqz,
                               Pty * nqz - Ptz * nqy,
                               Ptz * nqx - Ptx * nqz,
                               Ptx * nqy - Pty * nqx };
                accum_point(acc, J, r, 10.0f, 27);
            }
            // ---- RGB (photometric) term ----
            float u0f = floorf(u), v0f = floorf(v);
            float du = u - u0f, dv = v - v0f;
            int u0 = (int)u0f; u0 = u0 < 0 ? 0 : (u0 > WW - 1 ? WW - 1 : u0);
            int u1 = (u0 + 1 > WW - 1) ? WW - 1 : u0 + 1;
            int v0 = (int)v0f; v0 = v0 < 0 ? 0 : (v0 > HH - 1 ? HH - 1 : v0);
            int v1 = (v0 + 1 > HH - 1) ? HH - 1 : v0 + 1;
            int i00 = v0 * WW + u0, i01 = v0 * WW + u1, i10 = v1 * WW + u0, i11 = v1 * WW + u1;
            float I00, I01, I10, I11, gx00, gx01, gx10, gx11, gy00, gy01, gy10, gy11;
            if (PACKED) {
                float4 c00 = g4[i00], c01 = g4[i01], c10 = g4[i10], c11 = g4[i11];
                I00 = c00.x; gx00 = c00.y; gy00 = c00.z;
                I01 = c01.x; gx01 = c01.y; gy01 = c01.z;
                I10 = c10.x; gx10 = c10.y; gy10 = c10.z;
                I11 = c11.x; gx11 = c11.y; gy11 = c11.z;
            } else {
                const float* g = gray_target;
                I00 = g[i00]; I01 = g[i01]; I10 = g[i10]; I11 = g[i11];
                gx00 = gradu(g, v0, u0); gx01 = gradu(g, v0, u1);
                gx10 = gradu(g, v1, u0); gx11 = gradu(g, v1, u1);
                gy00 = gradv(g, v0, u0); gy01 = gradv(g, v0, u1);
                gy10 = gradv(g, v1, u0); gy11 = gradv(g, v1, u1);
            }
            float It  = (I00 * (1.f - du) + I01 * du) * (1.f - dv) + (I10 * (1.f - du) + I11 * du) * dv;
            float gxs = (gx00 * (1.f - du) + gx01 * du) * (1.f - dv) + (gx10 * (1.f - du) + gx11 * du) * dv;
            float gys = (gy00 * (1.f - du) + gy01 * du) * (1.f - dv) + (gy10 * (1.f - du) + gy11 * du) * dv;
            float rr = It - gray_ref[p];
            float gpx = gxs * fx / Zs;
            float gpy = gys * fy / Zs;
            float gpz = -(gxs * fx * Ptx + gys * fy * Pty) / (Zs * Zs);
            float J[6] = { gpx, gpy, gpz,
                           Pty * gpz - Ptz * gpy,
                           Ptz * gpx - Ptx * gpz,
                           Ptx * gpy - Pty * gpx };
            accum_point(acc, J, rr, 1.0f, 28);
        }
    }

    // ---- deterministic in-block reduction: wave shuffle -> LDS -> partial ----
    #pragma unroll
    for (int q = 0; q < NACC; q++) {
        float vq = acc[q];
        #pragma unroll
        for (int off = 32; off >= 1; off >>= 1) vq += __shfl_xor(vq, off);
        acc[q] = vq;
    }
    int wave = tid >> 6;
    int lane = tid & 63;
    if (lane == 0) {
        #pragma unroll
        for (int q = 0; q < NACC; q++) lds[wave][q] = acc[q];
    }
    __syncthreads();
    if (tid < NACC) {
        int q = tid;
        float s = ((lds[0][q] + lds[1][q]) + (lds[2][q] + lds[3][q]))
                + ((lds[4][q] + lds[5][q]) + (lds[6][q] + lds[7][q]));
        st_f_sc1(&pbuf[q * PB + bid], s);   // coherent-point store, L2 untouched
    }
    __syncthreads();   // drains this block's sc1 stores (vmcnt) before arrive
    if (tid == 0) {
        int a = __hip_atomic_fetch_add(cnt, 1, __ATOMIC_RELAXED, __HIP_MEMORY_SCOPE_AGENT);
        slast = (a == NB_B - 1) ? 1 : 0;
    }
    __syncthreads();
    if (!slast) return;                     // non-finishers exit; no waiting

    // ================= finisher block only: reduce + solve =================
    __shared__ double p16[NACC * NSPL];
    __shared__ double sums[NACC];
    __shared__ double M[6][7];
    __shared__ double x0s[6];
    if (tid < NACC * NSPL) {
        int q = tid >> 4, s = tid & 15;
        int lo = s * CHS;
        int hi = lo + CHS; if (hi > PB) hi = PB;    // s=15: 570..600
        const float* row = pbuf + q * PB + lo;
        double a0 = 0.0, a1 = 0.0, a2 = 0.0, a3 = 0.0;
        int n = hi - lo;
        int i = 0;
        for (; i + 4 <= n; i += 4) {
            a0 += (double)ld_f_sc1(&row[i]);
            a1 += (double)ld_f_sc1(&row[i + 1]);
            a2 += (double)ld_f_sc1(&row[i + 2]);
            a3 += (double)ld_f_sc1(&row[i + 3]);
        }
        for (; i < n; i++) a0 += (double)ld_f_sc1(&row[i]);   // remainder kept!
        p16[tid] = ((a0 + a1) + (a2 + a3));
    }
    __syncthreads();
    if (tid < NACC) {
        double sm = 0.0;
        #pragma unroll
        for (int s = 0; s < NSPL; s++) sm += p16[tid * NSPL + s];
        sums[tid] = sm;
    }
    __syncthreads();
    if (tid == 0) {
        int k = 0;
        for (int i = 0; i < 6; i++)
            for (int j = i; j < 6; j++) { M[i][j] = sums[k]; M[j][i] = sums[k]; k++; }
        for (int i = 0; i < 6; i++) { M[i][6] = sums[21 + i]; M[i][i] += 1e-9; }
        double new_cost = 10.0 * sums[27] / (double)NPIX + sums[28] / (double)NPIX;

        // 6x6 Gaussian elimination with partial pivoting (f64, in LDS)
        for (int c = 0; c < 6; c++) {
            int piv = c; double mx = fabs(M[c][c]);
            for (int r2 = c + 1; r2 < 6; r2++) {
                double a = fabs(M[r2][c]);
                if (a > mx) { mx = a; piv = r2; }
            }
            if (piv != c)
                for (int j2 = 0; j2 < 7; j2++) { double tmp = M[c][j2]; M[c][j2] = M[piv][j2]; M[piv][j2] = tmp; }
            double inv = 1.0 / M[c][c];
            for (int r2 = c + 1; r2 < 6; r2++) {
                double f = M[r2][c] * inv;
                for (int j2 = c; j2 < 7; j2++) M[r2][j2] -= f * M[c][j2];
            }
        }
        for (int i = 5; i >= 0; i--) {
            double s = M[i][6];
            for (int j = i + 1; j < 6; j++) s -= M[i][j] * x0s[j];
            x0s[i] = s / M[i][i];
        }

        double nx0 = 0.0, nx = 0.0;
        float xf[6];
        for (int i = 0; i < 6; i++) {
            xf[i] = ws[16 + i];
            nx0 += x0s[i] * x0s[i];
            nx  += (double)xf[i] * (double)xf[i];
        }
        nx0 = sqrt(nx0); nx = sqrt(nx);
        bool convold = (ws[12] != 0.f);
        bool c2 = convold || (new_cost < 1e-3) || (nx0 < 1e-8 * (1e-8 + nx));
        float xn[6];
        for (int i = 0; i < 6; i++)
            xn[i] = c2 ? xf[i] : (float)((double)xf[i] - x0s[i]);
        for (int i = 0; i < 6; i++) ws[16 + i] = xn[i];
        ws[12] = c2 ? 1.f : 0.f;
        if (!convold) ws[13] = (float)new_cost;

        float T[16];
        exp_se3_f32(xn, T);
        ws[0] = T[0]; ws[1] = T[1]; ws[2]  = T[2];
        ws[3] = T[4]; ws[4] = T[5]; ws[5]  = T[6];
        ws[6] = T[8]; ws[7] = T[9]; ws[8]  = T[10];
        ws[9] = T[3]; ws[10] = T[7]; ws[11] = T[11];
        // plain stores: kernel-end release makes them visible to next dispatch

        if (it == 19) {
            for (int i = 0; i < 16; i++) out[i] = T[i];
            out[16] = ws[13];
        }
    }
}

extern "C" void kernel_launch(void* const* d_in, const int* in_sizes, int n_in,
                              void* d_out, int out_size, void* d_ws, size_t ws_size,
                              hipStream_t stream) {
    const float* depth_ref      = (const float*)d_in[0];
    const float* normals_ref    = (const float*)d_in[1];
    const float* gray_ref       = (const float*)d_in[2];
    const float* gray_target    = (const float*)d_in[3];
    const float* points_target  = (const float*)d_in[4];
    const float* normals_target = (const float*)d_in[5];
    const float* K              = (const float*)d_in[6];
    float* ws  = (float*)d_ws;
    float* out = (float*)d_out;

    // zero iteration counters + state header (captured; replays deterministically)
    hipMemsetAsync(d_ws, 0, 256, stream);

    bool big = ws_size >= (size_t)WS_BIG_END * sizeof(float);
    if (big) {
        hipLaunchKernelGGL((pack_init<1>), dim3(NB_B), dim3(TPB_B), 0, stream,
                           depth_ref, normals_ref, gray_target,
                           points_target, normals_target, ws);
        for (int it = 0; it < 20; ++it) {
            hipLaunchKernelGGL((map_fused<1>), dim3(NB_B), dim3(TPB_B), 0, stream,
                               depth_ref, normals_ref, gray_ref, gray_target,
                               points_target, normals_target, K, ws, out, it);
        }
    } else {
        hipLaunchKernelGGL((pack_init<0>), dim3(NB_B), dim3(TPB_B), 0, stream,
                           depth_ref, normals_ref, gray_target,
                           points_target, normals_target, ws);
        for (int it = 0; it < 20; ++it) {
            hipLaunchKernelGGL((map_fused<0>), dim3(NB_B), dim3(TPB_B), 0, stream,
                               depth_ref, normals_ref, gray_ref, gray_target,
                               points_target, normals_target, K, ws, out, it);
        }
    }
}